// Round 1
// baseline (365.128 us; speedup 1.0000x reference)
//
#include <hip/hip_runtime.h>
#include <math.h>

// Problem constants (fixed by the reference's setup_inputs)
#define BGRAPHS 64
#define DDIM    512
#define NNODES  (64 * 2048)

// ---------------------------------------------------------------------------
// Kernel 1: pn[g][o] = sum_d graph_attr[g][d] * W[o][d] + b[o]
// One 64-lane wave per output element. 512 floats per dot = 2 float4 per lane.
// ---------------------------------------------------------------------------
__global__ __launch_bounds__(256) void linear_pn_kernel(
    const float* __restrict__ ga,   // [B, D]
    const float* __restrict__ W,    // [D, D] row-major: W[o*D + d]
    const float* __restrict__ b,    // [D]
    float* __restrict__ pn,         // [B, D]
    int total_out)                  // B*D
{
    int wave = (int)((blockIdx.x * blockDim.x + threadIdx.x) >> 6);
    int lane = threadIdx.x & 63;
    if (wave >= total_out) return;
    int g = wave >> 9;         // / 512
    int o = wave & 511;        // % 512

    const float4* gaRow = (const float4*)(ga + (size_t)g * DDIM);
    const float4* wRow  = (const float4*)(W  + (size_t)o * DDIM);

    float4 a0 = gaRow[lane];
    float4 w0 = wRow[lane];
    float4 a1 = gaRow[lane + 64];
    float4 w1 = wRow[lane + 64];

    float acc = a0.x * w0.x + a0.y * w0.y + a0.z * w0.z + a0.w * w0.w
              + a1.x * w1.x + a1.y * w1.y + a1.z * w1.z + a1.w * w1.w;

    #pragma unroll
    for (int m = 32; m; m >>= 1) acc += __shfl_xor(acc, m, 64);

    if (lane == 0) pn[wave] = acc + b[o];
}

// ---------------------------------------------------------------------------
// Kernel 2: out[i] = -sqrt(sum_d (x[i][d] - pn[batch[i]][d])^2) / temp
// One wave per node. x reads are fully coalesced (64 lanes x float4 = 1 KiB
// per instruction). pn rows (2 KiB each) are L1/L2 resident (128 KiB total).
// With batch sorted into equal 2048-node segments, dense[batch,pos] == sim
// reshaped, so we write out[i] directly (every slot is set; no FILL remains).
// ---------------------------------------------------------------------------
__global__ __launch_bounds__(256) void node_sim_kernel(
    const float* __restrict__ x,     // [N, D]
    const float* __restrict__ pn,    // [B, D]
    const int*   __restrict__ batch, // [N]
    const float* __restrict__ temp,  // [1]
    float* __restrict__ out,         // [N]  (== [B, MAX_NODES, 1] flat)
    int n_nodes)
{
    int wave = (int)((blockIdx.x * blockDim.x + threadIdx.x) >> 6);
    int lane = threadIdx.x & 63;
    if (wave >= n_nodes) return;

    int g = batch[wave];

    const float4* xRow = (const float4*)(x  + (size_t)wave * DDIM);
    const float4* pRow = (const float4*)(pn + (size_t)g    * DDIM);

    float4 x0 = xRow[lane];
    float4 x1 = xRow[lane + 64];
    float4 p0 = pRow[lane];
    float4 p1 = pRow[lane + 64];

    float d0 = x0.x - p0.x;
    float d1 = x0.y - p0.y;
    float d2 = x0.z - p0.z;
    float d3 = x0.w - p0.w;
    float d4 = x1.x - p1.x;
    float d5 = x1.y - p1.y;
    float d6 = x1.z - p1.z;
    float d7 = x1.w - p1.w;

    float acc = d0 * d0 + d1 * d1 + d2 * d2 + d3 * d3
              + d4 * d4 + d5 * d5 + d6 * d6 + d7 * d7;

    #pragma unroll
    for (int m = 32; m; m >>= 1) acc += __shfl_xor(acc, m, 64);

    if (lane == 0) out[wave] = -sqrtf(acc) / temp[0];
}

extern "C" void kernel_launch(void* const* d_in, const int* in_sizes, int n_in,
                              void* d_out, int out_size, void* d_ws, size_t ws_size,
                              hipStream_t stream) {
    const float* x     = (const float*)d_in[0];   // [N, D]
    const float* ga    = (const float*)d_in[1];   // [B, D]
    const int*   batch = (const int*)  d_in[2];   // [N]
    const float* W     = (const float*)d_in[3];   // [D, D]
    const float* b     = (const float*)d_in[4];   // [D]
    const float* temp  = (const float*)d_in[5];   // [1]
    float* out = (float*)d_out;                   // [B, MAX_NODES, 1] flat = [N]

    float* pn = (float*)d_ws;                     // [B, D] = 128 KiB scratch

    // Kernel 1: B*D = 32768 output elems, 1 wave each, 4 waves/block
    {
        int total = BGRAPHS * DDIM;
        int waves_per_block = 256 / 64;
        int blocks = (total + waves_per_block - 1) / waves_per_block;
        linear_pn_kernel<<<blocks, 256, 0, stream>>>(ga, W, b, pn, total);
    }

    // Kernel 2: one wave per node
    {
        int waves_per_block = 256 / 64;
        int blocks = (NNODES + waves_per_block - 1) / waves_per_block;
        node_sim_kernel<<<blocks, 256, 0, stream>>>(x, pn, batch, temp, out, NNODES);
    }
}

// Round 3
// 349.222 us; speedup vs baseline: 1.0455x; 1.0455x over previous
//
#include <hip/hip_runtime.h>
#include <math.h>

// Problem constants (fixed by the reference's setup_inputs)
#define BGRAPHS 64
#define DDIM    512
#define NNODES  (64 * 2048)

// Native clang vector type — accepted by __builtin_nontemporal_load
// (HIP's float4 is a struct wrapper, which the builtin rejects).
typedef float vfloat4 __attribute__((ext_vector_type(4)));

// ---------------------------------------------------------------------------
// Kernel 1: pn[g][o] = sum_d graph_attr[g][d] * W[o][d] + b[o]
// One 64-lane wave per output element. 512 floats per dot = 2 float4 per lane.
// W is 1 MB -> L2-resident after first touch; ga is 128 KB -> L1-resident.
// ~5 us, not the bottleneck.
// ---------------------------------------------------------------------------
__global__ __launch_bounds__(256) void linear_pn_kernel(
    const float* __restrict__ ga,   // [B, D]
    const float* __restrict__ W,    // [D, D] row-major: W[o*D + d]
    const float* __restrict__ b,    // [D]
    float* __restrict__ pn,         // [B, D]
    int total_out)                  // B*D
{
    int wave = (int)((blockIdx.x * blockDim.x + threadIdx.x) >> 6);
    int lane = threadIdx.x & 63;
    if (wave >= total_out) return;
    int g = wave >> 9;         // / 512
    int o = wave & 511;        // % 512

    const vfloat4* gaRow = (const vfloat4*)(ga + (size_t)g * DDIM);
    const vfloat4* wRow  = (const vfloat4*)(W  + (size_t)o * DDIM);

    vfloat4 a0 = gaRow[lane];
    vfloat4 w0 = wRow[lane];
    vfloat4 a1 = gaRow[lane + 64];
    vfloat4 w1 = wRow[lane + 64];

    float acc = a0.x * w0.x + a0.y * w0.y + a0.z * w0.z + a0.w * w0.w
              + a1.x * w1.x + a1.y * w1.y + a1.z * w1.z + a1.w * w1.w;

    #pragma unroll
    for (int m = 32; m; m >>= 1) acc += __shfl_xor(acc, m, 64);

    if (lane == 0) pn[wave] = acc + b[o];
}

// ---------------------------------------------------------------------------
// Kernel 2: out[i] = -sqrt(sum_d (x[i][d] - pn[batch[i]][d])^2) / temp
// One wave per node. x reads: nontemporal (streamed once, don't evict pn/W
// from L2). pn rows (2 KiB each, 128 KiB total) stay L1/L2 resident.
// batch index is wave-uniform -> readfirstlane so it becomes an s_load.
// With batch sorted into equal 2048-node segments, dense[batch,pos] == sim
// reshaped, so out[i] is written directly (every slot set; no FILL remains).
// ---------------------------------------------------------------------------
__global__ __launch_bounds__(256) void node_sim_kernel(
    const float* __restrict__ x,     // [N, D]
    const float* __restrict__ pn,    // [B, D]
    const int*   __restrict__ batch, // [N]
    const float* __restrict__ temp,  // [1]
    float* __restrict__ out,         // [N]  (== [B, MAX_NODES, 1] flat)
    int n_nodes)
{
    int wave = (int)((blockIdx.x * blockDim.x + threadIdx.x) >> 6);
    int lane = threadIdx.x & 63;
    if (wave >= n_nodes) return;

    // wave-uniform scalar index -> scalar load path
    int node = __builtin_amdgcn_readfirstlane(wave);
    int g = batch[node];

    const vfloat4* xRow = (const vfloat4*)(x  + (size_t)node * DDIM);
    const vfloat4* pRow = (const vfloat4*)(pn + (size_t)g    * DDIM);

    // x: streamed exactly once -> nontemporal, keep L2 for pn
    vfloat4 x0 = __builtin_nontemporal_load(xRow + lane);
    vfloat4 x1 = __builtin_nontemporal_load(xRow + lane + 64);
    vfloat4 p0 = pRow[lane];
    vfloat4 p1 = pRow[lane + 64];

    float d0 = x0.x - p0.x;
    float d1 = x0.y - p0.y;
    float d2 = x0.z - p0.z;
    float d3 = x0.w - p0.w;
    float d4 = x1.x - p1.x;
    float d5 = x1.y - p1.y;
    float d6 = x1.z - p1.z;
    float d7 = x1.w - p1.w;

    float acc = d0 * d0 + d1 * d1 + d2 * d2 + d3 * d3
              + d4 * d4 + d5 * d5 + d6 * d6 + d7 * d7;

    #pragma unroll
    for (int m = 32; m; m >>= 1) acc += __shfl_xor(acc, m, 64);

    if (lane == 0) out[node] = -sqrtf(acc) / temp[0];
}

extern "C" void kernel_launch(void* const* d_in, const int* in_sizes, int n_in,
                              void* d_out, int out_size, void* d_ws, size_t ws_size,
                              hipStream_t stream) {
    const float* x     = (const float*)d_in[0];   // [N, D]
    const float* ga    = (const float*)d_in[1];   // [B, D]
    const int*   batch = (const int*)  d_in[2];   // [N]
    const float* W     = (const float*)d_in[3];   // [D, D]
    const float* b     = (const float*)d_in[4];   // [D]
    const float* temp  = (const float*)d_in[5];   // [1]
    float* out = (float*)d_out;                   // [B, MAX_NODES, 1] flat = [N]

    float* pn = (float*)d_ws;                     // [B, D] = 128 KiB scratch

    // Kernel 1: B*D = 32768 output elems, 1 wave each, 4 waves/block
    {
        int total = BGRAPHS * DDIM;
        int waves_per_block = 256 / 64;
        int blocks = (total + waves_per_block - 1) / waves_per_block;
        linear_pn_kernel<<<blocks, 256, 0, stream>>>(ga, W, b, pn, total);
    }

    // Kernel 2: one wave per node
    {
        int waves_per_block = 256 / 64;
        int blocks = (NNODES + waves_per_block - 1) / waves_per_block;
        node_sim_kernel<<<blocks, 256, 0, stream>>>(x, pn, batch, temp, out, NNODES);
    }
}

// Round 4
// 345.791 us; speedup vs baseline: 1.0559x; 1.0099x over previous
//
#include <hip/hip_runtime.h>
#include <math.h>

// Problem constants (fixed by the reference's setup_inputs)
#define BGRAPHS 64
#define DDIM    512
#define NNODES  (64 * 2048)

// Native clang vector type — accepted by __builtin_nontemporal_load
// (HIP's float4 is a struct wrapper, which the builtin rejects).
typedef float vfloat4 __attribute__((ext_vector_type(4)));

// ---------------------------------------------------------------------------
// Kernel 1: pn[g][o] = sum_d graph_attr[g][d] * W[o][d] + b[o]
// One 64-lane wave per output element. 512 floats per dot = 2 float4 per lane.
// W is 1 MB -> L2-resident after first touch; ga is 128 KB -> L1-resident.
// ~5 us, not the bottleneck.
// ---------------------------------------------------------------------------
__global__ __launch_bounds__(256) void linear_pn_kernel(
    const float* __restrict__ ga,   // [B, D]
    const float* __restrict__ W,    // [D, D] row-major: W[o*D + d]
    const float* __restrict__ b,    // [D]
    float* __restrict__ pn,         // [B, D]
    int total_out)                  // B*D
{
    int wave = (int)((blockIdx.x * blockDim.x + threadIdx.x) >> 6);
    int lane = threadIdx.x & 63;
    if (wave >= total_out) return;
    int g = wave >> 9;         // / 512
    int o = wave & 511;        // % 512

    const vfloat4* gaRow = (const vfloat4*)(ga + (size_t)g * DDIM);
    const vfloat4* wRow  = (const vfloat4*)(W  + (size_t)o * DDIM);

    vfloat4 a0 = gaRow[lane];
    vfloat4 w0 = wRow[lane];
    vfloat4 a1 = gaRow[lane + 64];
    vfloat4 w1 = wRow[lane + 64];

    float acc = a0.x * w0.x + a0.y * w0.y + a0.z * w0.z + a0.w * w0.w
              + a1.x * w1.x + a1.y * w1.y + a1.z * w1.z + a1.w * w1.w;

    #pragma unroll
    for (int m = 32; m; m >>= 1) acc += __shfl_xor(acc, m, 64);

    if (lane == 0) pn[wave] = acc + b[o];
}

// ---------------------------------------------------------------------------
// Kernel 2: out[i] = -sqrt(sum_d (x[i][d] - pn[batch[i]][d])^2) / temp
// FOUR nodes per wave:
//  - 8 nontemporal float4 x-loads issued back-to-back (4x the MLP of the
//    1-node version; x is streamed exactly once, nt keeps L2 for pn/W)
//  - pn row (same graph for all 4 nodes: segments are 2048-aligned and
//    2048 % 4 == 0) loaded once per wave instead of once per node
//  - multi-value butterfly: 2 transpose-exchange stages fold the 4
//    accumulators, then 4 plain butterfly stages -> 7 shuffles for 4
//    results (vs 24), results landing in lanes 0..3
//  - lanes 0..3 write 4 consecutive floats (coalesced 16 B nt store)
// With batch sorted into equal 2048-node segments, dense[batch,pos] == sim
// reshaped, so out[i] is written directly (every slot set; no FILL remains).
// ---------------------------------------------------------------------------
__global__ __launch_bounds__(256) void node_sim_kernel(
    const float* __restrict__ x,     // [N, D]
    const float* __restrict__ pn,    // [B, D]
    const int*   __restrict__ batch, // [N]
    const float* __restrict__ temp,  // [1]
    float* __restrict__ out,         // [N]  (== [B, MAX_NODES, 1] flat)
    int n_groups)                    // N / 4
{
    int wave = (int)((blockIdx.x * blockDim.x + threadIdx.x) >> 6);
    int lane = threadIdx.x & 63;
    if (wave >= n_groups) return;

    int node0 = __builtin_amdgcn_readfirstlane(wave << 2);  // first of 4 nodes
    int g = batch[node0];

    const vfloat4* xRow0 = (const vfloat4*)(x + (size_t)node0 * DDIM);
    const vfloat4* pRow  = (const vfloat4*)(pn + (size_t)g * DDIM);

    // Issue all 8 x-loads + 2 pn-loads before any use: max outstanding VMEM.
    vfloat4 xa0 = __builtin_nontemporal_load(xRow0 + lane);
    vfloat4 xa1 = __builtin_nontemporal_load(xRow0 + lane + 64);
    vfloat4 xb0 = __builtin_nontemporal_load(xRow0 + lane + 128);
    vfloat4 xb1 = __builtin_nontemporal_load(xRow0 + lane + 192);
    vfloat4 xc0 = __builtin_nontemporal_load(xRow0 + lane + 256);
    vfloat4 xc1 = __builtin_nontemporal_load(xRow0 + lane + 320);
    vfloat4 xd0 = __builtin_nontemporal_load(xRow0 + lane + 384);
    vfloat4 xd1 = __builtin_nontemporal_load(xRow0 + lane + 448);
    vfloat4 p0 = pRow[lane];
    vfloat4 p1 = pRow[lane + 64];

    vfloat4 e;
    float acc0, acc1, acc2, acc3;
    e = xa0 - p0;
    acc0  = e.x * e.x + e.y * e.y + e.z * e.z + e.w * e.w;
    e = xa1 - p1;
    acc0 += e.x * e.x + e.y * e.y + e.z * e.z + e.w * e.w;
    e = xb0 - p0;
    acc1  = e.x * e.x + e.y * e.y + e.z * e.z + e.w * e.w;
    e = xb1 - p1;
    acc1 += e.x * e.x + e.y * e.y + e.z * e.z + e.w * e.w;
    e = xc0 - p0;
    acc2  = e.x * e.x + e.y * e.y + e.z * e.z + e.w * e.w;
    e = xc1 - p1;
    acc2 += e.x * e.x + e.y * e.y + e.z * e.z + e.w * e.w;
    e = xd0 - p0;
    acc3  = e.x * e.x + e.y * e.y + e.z * e.z + e.w * e.w;
    e = xd1 - p1;
    acc3 += e.x * e.x + e.y * e.y + e.z * e.z + e.w * e.w;

    // Stage 1 (xor 1): fold acc0/acc1 and acc2/acc3.
    // After: even lanes hold pair-sum of acc0 (resp acc2), odd lanes acc1/acc3.
    float t01 = (lane & 1) ? acc0 : acc1;
    t01 = __shfl_xor(t01, 1, 64);
    float a01 = ((lane & 1) ? acc1 : acc0) + t01;
    float t23 = (lane & 1) ? acc2 : acc3;
    t23 = __shfl_xor(t23, 1, 64);
    float a23 = ((lane & 1) ? acc3 : acc2) + t23;

    // Stage 2 (xor 2): fold a01/a23. After: lane with (lane&3)==j holds node j.
    float t = (lane & 2) ? a01 : a23;
    t = __shfl_xor(t, 2, 64);
    float a = ((lane & 2) ? a23 : a01) + t;

    // Stages 3-6: plain butterfly over xor 4,8,16,32.
    #pragma unroll
    for (int m = 4; m < 64; m <<= 1) a += __shfl_xor(a, m, 64);

    if (lane < 4) {
        float r = -sqrtf(a) / temp[0];
        __builtin_nontemporal_store(r, out + node0 + lane);
    }
}

extern "C" void kernel_launch(void* const* d_in, const int* in_sizes, int n_in,
                              void* d_out, int out_size, void* d_ws, size_t ws_size,
                              hipStream_t stream) {
    const float* x     = (const float*)d_in[0];   // [N, D]
    const float* ga    = (const float*)d_in[1];   // [B, D]
    const int*   batch = (const int*)  d_in[2];   // [N]
    const float* W     = (const float*)d_in[3];   // [D, D]
    const float* b     = (const float*)d_in[4];   // [D]
    const float* temp  = (const float*)d_in[5];   // [1]
    float* out = (float*)d_out;                   // [B, MAX_NODES, 1] flat = [N]

    float* pn = (float*)d_ws;                     // [B, D] = 128 KiB scratch

    // Kernel 1: B*D = 32768 output elems, 1 wave each, 4 waves/block
    {
        int total = BGRAPHS * DDIM;
        int waves_per_block = 256 / 64;
        int blocks = (total + waves_per_block - 1) / waves_per_block;
        linear_pn_kernel<<<blocks, 256, 0, stream>>>(ga, W, b, pn, total);
    }

    // Kernel 2: one wave per 4 nodes
    {
        int n_groups = NNODES / 4;                // 32768 waves
        int waves_per_block = 256 / 64;
        int blocks = (n_groups + waves_per_block - 1) / waves_per_block;
        node_sim_kernel<<<blocks, 256, 0, stream>>>(x, pn, batch, temp, out, n_groups);
    }
}